// Round 1
// baseline (58.109 us; speedup 1.0000x reference)
//
#include <hip/hip_runtime.h>

#define NH 32          // heads
#define NV 1537        // edge_enc_w rows
#define ND 20          // MULTI_HOP_MAX_DIST
#define NB 16          // batch
#define NN 64          // nodes

// ---------------- Kernel 1: T[d][v][h] = sum_k enc[v][k] * Wd[d][k][h] ----------------
// rows = d*NV + v (30740 total), 8 rows per 256-thread block, lane h = tid&31.
__global__ void build_T_kernel(const float* __restrict__ enc,
                               const float* __restrict__ wdis,
                               float* __restrict__ T) {
    int row = blockIdx.x * 8 + (threadIdx.x >> 5);
    int h   = threadIdx.x & 31;
    if (row >= ND * NV) return;
    int d = row / NV;
    int v = row - d * NV;
    const float* e = enc + v * NH;            // broadcast across the 32 h-lanes
    const float* w = wdis + d * NH * NH + h;  // coalesced across h
    float acc = 0.f;
#pragma unroll
    for (int k = 0; k < NH; ++k) acc += e[k] * w[k * NH];
    T[row * NH + h] = acc;
}

// ---------------- Kernel 2: interior (i,j in 1..64) ----------------
// 8 cells per 256-thread block; 32 lanes per cell, lane = head h.
__global__ void __launch_bounds__(256)
main_kernel(const float* __restrict__ ab,      // (B,65,65)
            const int*   __restrict__ spos,    // (B,64,64)
            const int*   __restrict__ eidx,    // (B,64,64,20,3)
            const float* __restrict__ mask2d,  // (B,)
            const float* __restrict__ spw,     // (512,32)
            const float* __restrict__ T,       // (20,1537,32) in ws
            float*       __restrict__ out) {   // (B,32,65,65)
    __shared__ int sidx[480];                  // 8 cells x 60 indices
    int tid = threadIdx.x;
    const int* ep = eidx + (size_t)blockIdx.x * 480;   // block's cells are contiguous
    sidx[tid] = ep[tid];
    if (tid < 224) sidx[256 + tid] = ep[256 + tid];
    __syncthreads();

    int c = tid >> 5, h = tid & 31;
    int cell = blockIdx.x * 8 + c;
    int b = cell >> 12, ij = cell & 4095, i = ij >> 6, j = ij & 63;

    const int* mi = sidx + c * 60;
    float acc = 0.f;
#pragma unroll
    for (int d = 0; d < ND; ++d) {
        const float* Td = T + (size_t)d * NV * NH + h;
        acc += Td[mi[d * 3 + 0] * NH];   // 128B line per 32-lane group
        acc += Td[mi[d * 3 + 1] * NH];
        acc += Td[mi[d * 3 + 2] * NH];
    }

    int s  = spos[cell];
    int sp = (s == 0) ? 1 : s;
    sp = (sp > 1) ? sp - 1 : sp;
    sp = (sp > ND) ? ND : sp;

    float m   = mask2d[b];
    float spb = spw[s * NH + h] * m;
    float ebv = acc * m / (3.0f * (float)sp);
    float a   = ab[(b * 65 + i + 1) * 65 + (j + 1)];
    out[(((b * NH + h) * 65) + i + 1) * 65 + (j + 1)] = 2.0f * a + spb + ebv;
}

// ---------------- Kernel 3: borders (row 0 all j; col 0 for i>=1) ----------------
__global__ void border_kernel(const float* __restrict__ ab,
                              const float* __restrict__ tokw,
                              float* __restrict__ out) {
    int t = blockIdx.x * 256 + threadIdx.x;
    const int nA = NB * NH * 65;   // row 0
    if (t < nA) {
        int j = t % 65; int bh = t / 65; int h = bh & 31; int b = bh >> 5;
        out[((b * NH + h) * 65 + 0) * 65 + j] = 2.0f * ab[b * 4225 + j] + tokw[h];
    } else {
        t -= nA;
        if (t >= NB * NH * 64) return;
        int i = (t % 64) + 1; int bh = t / 64; int h = bh & 31; int b = bh >> 5;
        out[((b * NH + h) * 65 + i) * 65 + 0] = 2.0f * ab[b * 4225 + i * 65] + tokw[h];
    }
}

extern "C" void kernel_launch(void* const* d_in, const int* in_sizes, int n_in,
                              void* d_out, int out_size, void* d_ws, size_t ws_size,
                              hipStream_t stream) {
    const float* attn_bias   = (const float*)d_in[0];
    const int*   spatial_pos = (const int*)  d_in[1];
    // d_in[2] = x (unused), d_in[4] = attn_edge_type (unused)
    const int*   edge_input  = (const int*)  d_in[3];
    const float* mask_2d     = (const float*)d_in[5];
    const float* edge_enc_w  = (const float*)d_in[6];
    const float* edge_dis_w  = (const float*)d_in[7];
    const float* spatial_w   = (const float*)d_in[8];
    const float* token_w     = (const float*)d_in[9];
    float* out = (float*)d_out;
    float* T   = (float*)d_ws;    // 20*1537*32*4 = 3,934,720 B

    // Kernel 1: build gather table T
    {
        int rows = ND * NV;                       // 30740
        int blocks = (rows + 7) / 8;              // 3843
        build_T_kernel<<<blocks, 256, 0, stream>>>(edge_enc_w, edge_dis_w, T);
    }
    // Kernel 2: interior
    {
        int cells = NB * NN * NN;                 // 65536
        main_kernel<<<cells / 8, 256, 0, stream>>>(attn_bias, spatial_pos, edge_input,
                                                   mask_2d, spatial_w, T, out);
    }
    // Kernel 3: borders
    {
        int total = NB * NH * 65 + NB * NH * 64;  // 66048
        border_kernel<<<(total + 255) / 256, 256, 0, stream>>>(attn_bias, token_w, out);
    }
}

// Round 2
// 45.069 us; speedup vs baseline: 1.2894x; 1.2894x over previous
//
#include <hip/hip_runtime.h>
#include <hip/hip_bf16.h>

#define NH 32          // heads
#define NV 1537        // edge_enc_w rows
#define ND 20          // MULTI_HOP_MAX_DIST
#define NB 16          // batch
#define NN 64          // nodes
#define HALF 32        // cells per main block (half a row)

// ---------------- Kernel 1: T[d][v][h] = sum_k enc[v][k] * Wd[d][k][h], bf16 out ---------
__global__ void build_T_kernel(const float* __restrict__ enc,
                               const float* __restrict__ wdis,
                               __hip_bfloat16* __restrict__ T) {
    int row = blockIdx.x * 8 + (threadIdx.x >> 5);
    int h   = threadIdx.x & 31;
    if (row >= ND * NV) return;
    int d = row / NV;
    int v = row - d * NV;
    const float* e = enc + v * NH;            // broadcast across the 32 h-lanes
    const float* w = wdis + d * NH * NH + h;  // coalesced across h
    float acc = 0.f;
#pragma unroll
    for (int k = 0; k < NH; ++k) acc += e[k] * w[k * NH];
    T[row * NH + h] = __float2bfloat16(acc);
}

// ---------------- Kernel 2: interior, half-row blocks ----------------
// block = (b, i, half): 32 cells x 32 heads. Phase A: per-head coalesced T gathers
// into padded LDS tile. Phase B: transpose-read LDS, full-line coalesced writes.
__global__ void __launch_bounds__(256)
main_kernel(const float* __restrict__ ab,      // (B,65,65)
            const int*   __restrict__ spos,    // (B,64,64)
            const int*   __restrict__ eidx,    // (B,64,64,20,3)
            const float* __restrict__ mask2d,  // (B,)
            const float* __restrict__ spw,     // (512,32)
            const __hip_bfloat16* __restrict__ T,  // (20,1537,32) bf16 in ws
            float*       __restrict__ out) {   // (B,32,65,65)
    __shared__ int   sidx[HALF * 60];          // 7680 B, edge indices for 32 cells
    __shared__ float comb[HALF * 33];          // 4224 B, [j][h] padded stride 33

    int tid  = threadIdx.x;
    int blk  = blockIdx.x;         // 0..2047
    int half = blk & 1;
    int bi   = blk >> 1;           // b*64 + i
    int b = bi >> 6, i = bi & 63;
    int j0 = half * HALF;

    // stage this half-row's edge indices (contiguous, coalesced)
    const int* ep = eidx + (size_t)(bi * 64 + j0) * 60;
    for (int t = tid; t < HALF * 60; t += 256) sidx[t] = ep[t];
    __syncthreads();

    int g = tid >> 5, h = tid & 31;
    float m = mask2d[b];

    // phase A: 8 groups of 32 lanes (lane = head); each group does 4 cells
    for (int jj = g; jj < HALF; jj += 8) {
        const int* mi = sidx + jj * 60;
        float acc = 0.f;
#pragma unroll
        for (int d = 0; d < ND; ++d) {
            const __hip_bfloat16* Td = T + (size_t)d * NV * NH + h;
            acc += __bfloat162float(Td[mi[d * 3 + 0] * NH]);   // 64B line per group
            acc += __bfloat162float(Td[mi[d * 3 + 1] * NH]);
            acc += __bfloat162float(Td[mi[d * 3 + 2] * NH]);
        }
        int j  = j0 + jj;
        int s  = spos[bi * 64 + j];
        int sp = (s == 0) ? 1 : s;
        sp = (sp > 1) ? sp - 1 : sp;
        sp = (sp > ND) ? ND : sp;
        float spb = spw[s * NH + h];                            // coalesced 128B
        comb[jj * 33 + h] = (spb + acc / (3.0f * (float)sp)) * m;
    }
    __syncthreads();

    // phase B: tid -> (jw = tid&31, hbase = tid>>5); 4 passes over heads.
    // each 32-lane quarter-wave writes 32 consecutive floats (128B line).
    int jw    = tid & 31;
    int hbase = tid >> 5;
    float a2 = 2.0f * ab[(b * 65 + i + 1) * 65 + (j0 + jw + 1)];
#pragma unroll
    for (int p = 0; p < 4; ++p) {
        int h2 = p * 8 + hbase;
        out[((size_t)(b * NH + h2) * 65 + i + 1) * 65 + (j0 + jw + 1)] =
            a2 + comb[jw * 33 + h2];                            // bank-conflict-free
    }
}

// ---------------- Kernel 3: borders (row 0 all j; col 0 for i>=1) ----------------
__global__ void border_kernel(const float* __restrict__ ab,
                              const float* __restrict__ tokw,
                              float* __restrict__ out) {
    int t = blockIdx.x * 256 + threadIdx.x;
    const int nA = NB * NH * 65;   // row 0
    if (t < nA) {
        int j = t % 65; int bh = t / 65; int h = bh & 31; int b = bh >> 5;
        out[((b * NH + h) * 65 + 0) * 65 + j] = 2.0f * ab[b * 4225 + j] + tokw[h];
    } else {
        t -= nA;
        if (t >= NB * NH * 64) return;
        int i = (t % 64) + 1; int bh = t / 64; int h = bh & 31; int b = bh >> 5;
        out[((b * NH + h) * 65 + i) * 65 + 0] = 2.0f * ab[b * 4225 + i * 65] + tokw[h];
    }
}

extern "C" void kernel_launch(void* const* d_in, const int* in_sizes, int n_in,
                              void* d_out, int out_size, void* d_ws, size_t ws_size,
                              hipStream_t stream) {
    const float* attn_bias   = (const float*)d_in[0];
    const int*   spatial_pos = (const int*)  d_in[1];
    // d_in[2] = x (unused), d_in[4] = attn_edge_type (unused)
    const int*   edge_input  = (const int*)  d_in[3];
    const float* mask_2d     = (const float*)d_in[5];
    const float* edge_enc_w  = (const float*)d_in[6];
    const float* edge_dis_w  = (const float*)d_in[7];
    const float* spatial_w   = (const float*)d_in[8];
    const float* token_w     = (const float*)d_in[9];
    float* out = (float*)d_out;
    __hip_bfloat16* T = (__hip_bfloat16*)d_ws;  // 20*1537*32*2 = 1,967,360 B

    // Kernel 1: build gather table T (bf16)
    {
        int rows = ND * NV;                       // 30740
        int blocks = (rows + 7) / 8;              // 3843
        build_T_kernel<<<blocks, 256, 0, stream>>>(edge_enc_w, edge_dis_w, T);
    }
    // Kernel 2: interior (half-row blocks)
    {
        int blocks = NB * NN * 2;                 // 2048
        main_kernel<<<blocks, 256, 0, stream>>>(attn_bias, spatial_pos, edge_input,
                                                mask_2d, spatial_w, T, out);
    }
    // Kernel 3: borders
    {
        int total = NB * NH * 65 + NB * NH * 64;  // 66048
        border_kernel<<<(total + 255) / 256, 256, 0, stream>>>(attn_bias, token_w, out);
    }
}

// Round 3
// 36.549 us; speedup vs baseline: 1.5899x; 1.2331x over previous
//
#include <hip/hip_runtime.h>
#include <hip/hip_bf16.h>

#define NH 32          // heads
#define NV 1537        // edge_enc_w rows
#define ND 20          // MULTI_HOP_MAX_DIST
#define NB 16          // batch
#define NN 64          // nodes

#define TROWS (ND*NV)                    // 30740
#define TBLOCKS ((TROWS + 7) / 8)        // 3843
#define BORDER_N (NB*NH*65 + NB*NH*64)   // 66048
#define BBLOCKS ((BORDER_N + 255) / 256) // 258

// ---------------- Kernel 1: build T (bf16) + borders, fused ----------------
__global__ void __launch_bounds__(256)
prep_kernel(const float* __restrict__ enc,     // (1537,32)
            const float* __restrict__ wdis,    // (20,32,32)
            const float* __restrict__ ab,      // (B,65,65)
            const float* __restrict__ tokw,    // (32,)
            __hip_bfloat16* __restrict__ T,    // (20,1537,32) out
            float* __restrict__ out) {         // (B,32,65,65)
    int blk = blockIdx.x;
    if (blk < TBLOCKS) {
        int row = blk * 8 + (threadIdx.x >> 5);
        int h   = threadIdx.x & 31;
        if (row >= TROWS) return;
        int d = row / NV, v = row - d * NV;
        const float4* e4 = (const float4*)(enc + v * NH);
        const float*  w  = wdis + d * NH * NH + h;
        float acc = 0.f;
#pragma unroll
        for (int k4 = 0; k4 < 8; ++k4) {
            float4 e = e4[k4];
            acc += e.x * w[(k4 * 4 + 0) * NH];
            acc += e.y * w[(k4 * 4 + 1) * NH];
            acc += e.z * w[(k4 * 4 + 2) * NH];
            acc += e.w * w[(k4 * 4 + 3) * NH];
        }
        T[row * NH + h] = __float2bfloat16(acc);
    } else {
        int t = (blk - TBLOCKS) * 256 + threadIdx.x;
        const int nA = NB * NH * 65;   // row 0, all j
        if (t < nA) {
            int j = t % 65; int bh = t / 65; int h = bh & 31; int b = bh >> 5;
            out[((size_t)(b * NH + h) * 65 + 0) * 65 + j] =
                2.0f * ab[b * 4225 + j] + tokw[h];
        } else {
            t -= nA;                   // col 0, i >= 1
            if (t >= NB * NH * 64) return;
            int i = (t % 64) + 1; int bh = t / 64; int h = bh & 31; int b = bh >> 5;
            out[((size_t)(b * NH + h) * 65 + i) * 65 + 0] =
                2.0f * ab[b * 4225 + i * 65] + tokw[h];
        }
    }
}

// ---------------- Kernel 2: interior, quarter-row blocks ----------------
// block = (b, i, quarter): 16 cells. group = 16 lanes = 1 cell; lane l covers
// heads {2l, 2l+1} via one uint (bf16x2) per gather -> full 64B T-row per group.
__device__ __forceinline__ void gadd(unsigned int u, float& ax, float& ay) {
    ax += __uint_as_float(u << 16);
    ay += __uint_as_float(u & 0xffff0000u);
}

__global__ void __launch_bounds__(256, 2)
main_kernel(const float* __restrict__ ab,          // (B,65,65)
            const int*   __restrict__ spos,        // (B,64,64)
            const int*   __restrict__ eidx,        // (B,64,64,20,3)
            const float* __restrict__ mask2d,      // (B,)
            const float* __restrict__ spw,         // (512,32)
            const unsigned int* __restrict__ T2,   // T as (row=d*NV+v, 16 uints)
            float*       __restrict__ out) {       // (B,32,65,65)
    __shared__ int4  sidx4[240];        // 16 cells x 15 int4 = 60 ints each
    __shared__ float comb[32 * 17];     // [h][j] padded

    int tid = threadIdx.x;
    int blk = blockIdx.x;               // 4096
    int qtr = blk & 3, bi = blk >> 2;   // bi = b*64 + i
    int b = bi >> 6, i = bi & 63;
    int j0 = qtr * 16;

    const int4* ep = (const int4*)(eidx + (size_t)(bi * 64 + j0) * 60);
    if (tid < 240) sidx4[tid] = ep[tid];
    __syncthreads();

    int g = tid >> 4, l = tid & 15;     // group = cell jj, lane = head-pair

    int4 qd[15];
#pragma unroll
    for (int t = 0; t < 15; ++t) qd[t] = sidx4[g * 15 + t];

    const unsigned int* Tl = T2 + l;    // per-lane column of T rows
    float accx = 0.f, accy = 0.f;
#pragma unroll
    for (int t = 0; t < 15; ++t) {      // p = 4t..4t+3, d = p/3 (folds: t const)
        gadd(Tl[(((4 * t + 0) / 3) * NV + qd[t].x) * 16], accx, accy);
        gadd(Tl[(((4 * t + 1) / 3) * NV + qd[t].y) * 16], accx, accy);
        gadd(Tl[(((4 * t + 2) / 3) * NV + qd[t].z) * 16], accx, accy);
        gadd(Tl[(((4 * t + 3) / 3) * NV + qd[t].w) * 16], accx, accy);
    }

    int s  = spos[bi * 64 + j0 + g];
    int sp = (s == 0) ? 1 : s;
    sp = (sp > 1) ? sp - 1 : sp;
    sp = (sp > ND) ? ND : sp;
    float m   = mask2d[b];
    float esc = m / (3.0f * (float)sp);
    float2 spv = ((const float2*)(spw + s * NH))[l];   // heads 2l, 2l+1
    comb[(2 * l + 0) * 17 + g] = spv.x * m + accx * esc;
    comb[(2 * l + 1) * 17 + g] = spv.y * m + accy * esc;
    __syncthreads();

    // write phase: jw = tid&15 consecutive j -> 64B segments per (wave, h)
    int jw = tid & 15, hh = tid >> 4;
    float a2 = 2.0f * ab[(b * 65 + i + 1) * 65 + (j0 + jw + 1)];
    out[((size_t)(b * NH + hh) * 65 + i + 1) * 65 + (j0 + jw + 1)] =
        a2 + comb[hh * 17 + jw];
    out[((size_t)(b * NH + hh + 16) * 65 + i + 1) * 65 + (j0 + jw + 1)] =
        a2 + comb[(hh + 16) * 17 + jw];
}

extern "C" void kernel_launch(void* const* d_in, const int* in_sizes, int n_in,
                              void* d_out, int out_size, void* d_ws, size_t ws_size,
                              hipStream_t stream) {
    const float* attn_bias   = (const float*)d_in[0];
    const int*   spatial_pos = (const int*)  d_in[1];
    // d_in[2] = x (unused), d_in[4] = attn_edge_type (unused)
    const int*   edge_input  = (const int*)  d_in[3];
    const float* mask_2d     = (const float*)d_in[5];
    const float* edge_enc_w  = (const float*)d_in[6];
    const float* edge_dis_w  = (const float*)d_in[7];
    const float* spatial_w   = (const float*)d_in[8];
    const float* token_w     = (const float*)d_in[9];
    float* out = (float*)d_out;
    __hip_bfloat16* T = (__hip_bfloat16*)d_ws;  // 20*1537*32*2 = 1,967,360 B

    // Kernel 1: build T (bf16) + borders
    prep_kernel<<<TBLOCKS + BBLOCKS, 256, 0, stream>>>(edge_enc_w, edge_dis_w,
                                                       attn_bias, token_w, T, out);
    // Kernel 2: interior (quarter-row blocks)
    main_kernel<<<NB * NN * 4, 256, 0, stream>>>(attn_bias, spatial_pos, edge_input,
                                                 mask_2d, spatial_w,
                                                 (const unsigned int*)T, out);
}

// Round 4
// 35.115 us; speedup vs baseline: 1.6548x; 1.0409x over previous
//
#include <hip/hip_runtime.h>
#include <hip/hip_bf16.h>

#define NH 32          // heads
#define NV 1537        // edge_enc_w rows
#define ND 20          // MULTI_HOP_MAX_DIST
#define NB 16          // batch
#define NN 64          // nodes

#define TROWS (ND*NV)                    // 30740
#define TBLOCKS ((TROWS + 7) / 8)        // 3843
#define BORDER_N (NB*NH*65 + NB*NH*64)   // 66048
#define BBLOCKS ((BORDER_N + 255) / 256) // 258

typedef int   v4i __attribute__((ext_vector_type(4)));
typedef float v4f __attribute__((ext_vector_type(4)));

// ---------------- Kernel 1: build T (bf16) + borders, fused ----------------
__global__ void __launch_bounds__(256)
prep_kernel(const float* __restrict__ enc,     // (1537,32)
            const float* __restrict__ wdis,    // (20,32,32)
            const float* __restrict__ ab,      // (B,65,65)
            const float* __restrict__ tokw,    // (32,)
            __hip_bfloat16* __restrict__ T,    // (20,1537,32) out
            float* __restrict__ out) {         // (B,32,65,65)
    int blk = blockIdx.x;
    if (blk < TBLOCKS) {
        int row = blk * 8 + (threadIdx.x >> 5);
        int h   = threadIdx.x & 31;
        if (row >= TROWS) return;
        int d = row / NV, v = row - d * NV;
        const float4* e4 = (const float4*)(enc + v * NH);
        const float*  w  = wdis + d * NH * NH + h;
        float acc = 0.f;
#pragma unroll
        for (int k4 = 0; k4 < 8; ++k4) {
            float4 e = e4[k4];
            acc += e.x * w[(k4 * 4 + 0) * NH];
            acc += e.y * w[(k4 * 4 + 1) * NH];
            acc += e.z * w[(k4 * 4 + 2) * NH];
            acc += e.w * w[(k4 * 4 + 3) * NH];
        }
        T[row * NH + h] = __float2bfloat16(acc);
    } else {
        int t = (blk - TBLOCKS) * 256 + threadIdx.x;
        const int nA = NB * NH * 65;   // row 0, all j
        if (t < nA) {
            int j = t % 65; int bh = t / 65; int h = bh & 31; int b = bh >> 5;
            __builtin_nontemporal_store(2.0f * ab[b * 4225 + j] + tokw[h],
                &out[((size_t)(b * NH + h) * 65 + 0) * 65 + j]);
        } else {
            t -= nA;                   // col 0, i >= 1
            if (t >= NB * NH * 64) return;
            int i = (t % 64) + 1; int bh = t / 64; int h = bh & 31; int b = bh >> 5;
            __builtin_nontemporal_store(2.0f * ab[b * 4225 + i * 65] + tokw[h],
                &out[((size_t)(b * NH + h) * 65 + i) * 65 + 0]);
        }
    }
}

// ---------------- Kernel 2: interior, half-row blocks ----------------
// block = (b, i, half): 32 cells x 32 heads, 256 threads.
// group = 8 lanes = 1 cell; lane l covers heads {4l..4l+3} via one uint2
// (bf16x4) per gather -> full 64B T-row per 8-lane group. Indices read
// per-lookup from LDS (broadcast within group, conflict-free across groups).
__global__ void __launch_bounds__(256, 4)
main_kernel(const float* __restrict__ ab,          // (B,65,65)
            const int*   __restrict__ spos,        // (B,64,64)
            const int*   __restrict__ eidx,        // (B,64,64,20,3)
            const float* __restrict__ mask2d,      // (B,)
            const float* __restrict__ spw,         // (512,32)
            const uint2* __restrict__ T2,          // T rows as 8x uint2
            float*       __restrict__ out) {       // (B,32,65,65)
    __shared__ __align__(16) int sidx[32 * 60];    // 7680 B
    __shared__ float comb[32 * 33];                // [h][j] padded, 4224 B

    int tid  = threadIdx.x;
    int blk  = blockIdx.x;              // 0..2047
    int half = blk & 1;
    int bi   = blk >> 1;                // b*64 + i
    int b = bi >> 6, i = bi & 63;
    int j0 = half * 32;

    // stage 32 cells x 60 indices = 480 int4, nontemporal (protect T in L2)
    const v4i* ep4 = (const v4i*)(eidx + (size_t)(bi * 64 + j0) * 60);
    v4i* s4 = (v4i*)sidx;
    s4[tid] = __builtin_nontemporal_load(ep4 + tid);
    if (tid < 224) s4[256 + tid] = __builtin_nontemporal_load(ep4 + 256 + tid);
    __syncthreads();

    int g = tid >> 3, l = tid & 7;      // cell jj = g, lane = head-quad
    const int* mi = sidx + g * 60;
    const uint2* Tl = T2 + l;           // per-lane uint2 column; row stride 8

    float a0 = 0.f, a1 = 0.f, a2 = 0.f, a3 = 0.f;
#pragma unroll
    for (int p = 0; p < 60; ++p) {
        int d = p / 3;                  // compile-time per unrolled iter
        uint2 u = Tl[(size_t)(d * NV + mi[p]) * 8];
        a0 += __uint_as_float(u.x << 16);
        a1 += __uint_as_float(u.x & 0xffff0000u);
        a2 += __uint_as_float(u.y << 16);
        a3 += __uint_as_float(u.y & 0xffff0000u);
    }

    int s  = spos[bi * 64 + j0 + g];
    int sp = (s == 0) ? 1 : s;
    sp = (sp > 1) ? sp - 1 : sp;
    sp = (sp > ND) ? ND : sp;
    float m   = mask2d[b];
    float esc = m / (3.0f * (float)sp);
    v4f spv = ((const v4f*)(spw + s * NH))[l];     // heads 4l..4l+3, 16B/lane
    comb[(4 * l + 0) * 33 + g] = spv.x * m + a0 * esc;
    comb[(4 * l + 1) * 33 + g] = spv.y * m + a1 * esc;
    comb[(4 * l + 2) * 33 + g] = spv.z * m + a2 * esc;
    comb[(4 * l + 3) * 33 + g] = spv.w * m + a3 * esc;
    __syncthreads();

    // write phase: 32 consecutive j per 32-lane half-wave -> 128B segments
    int jw = tid & 31, hh = tid >> 5;   // hh in 0..7
    float a2b = 2.0f * ab[(b * 65 + i + 1) * 65 + (j0 + jw + 1)];
#pragma unroll
    for (int p = 0; p < 4; ++p) {
        int h = p * 8 + hh;
        __builtin_nontemporal_store(a2b + comb[h * 33 + jw],
            &out[((size_t)(b * NH + h) * 65 + i + 1) * 65 + (j0 + jw + 1)]);
    }
}

extern "C" void kernel_launch(void* const* d_in, const int* in_sizes, int n_in,
                              void* d_out, int out_size, void* d_ws, size_t ws_size,
                              hipStream_t stream) {
    const float* attn_bias   = (const float*)d_in[0];
    const int*   spatial_pos = (const int*)  d_in[1];
    // d_in[2] = x (unused), d_in[4] = attn_edge_type (unused)
    const int*   edge_input  = (const int*)  d_in[3];
    const float* mask_2d     = (const float*)d_in[5];
    const float* edge_enc_w  = (const float*)d_in[6];
    const float* edge_dis_w  = (const float*)d_in[7];
    const float* spatial_w   = (const float*)d_in[8];
    const float* token_w     = (const float*)d_in[9];
    float* out = (float*)d_out;
    __hip_bfloat16* T = (__hip_bfloat16*)d_ws;  // 20*1537*32*2 = 1,967,360 B

    // Kernel 1: build T (bf16) + borders
    prep_kernel<<<TBLOCKS + BBLOCKS, 256, 0, stream>>>(edge_enc_w, edge_dis_w,
                                                       attn_bias, token_w, T, out);
    // Kernel 2: interior (half-row blocks, 8-lane groups)
    main_kernel<<<NB * NN * 2, 256, 0, stream>>>(attn_bias, spatial_pos, edge_input,
                                                 mask_2d, spatial_w,
                                                 (const uint2*)T, out);
}